// Round 3
// baseline (182.997 us; speedup 1.0000x reference)
//
#include <hip/hip_runtime.h>
#include <hip/hip_bf16.h>

#define N_NODES 50000
#define N_EDGES 800000
#define D 128
#define BATCHSIZE 64

// Coarse binning: 128 dst-nodes per bucket (ws layout unchanged, proven)
#define CHUNK_BITS 7
#define CHUNK 128
#define NBUCKETS 391          // ceil(50000/128)
#define NBUCKETS_PAD 392
#define CAP 2400              // mean 2048 + ~7.8 sigma (proven rounds 4-10)

// bin v3: de-sliced. 391 tiles x 2048 edges, full-range histogram per block.
// Edge data read ONCE (6.4 MB, was 25.6 MB with 4-way slicing).
#define FB_TILE 2048
#define NTILES ((N_EDGES + FB_TILE - 1) / FB_TILE)   // 391
#define FB_THREADS 256
#define FB_GRID NTILES                                // 391
#define EPT 8                 // edges per thread (2048/256)

// gather: 2 half-bucket blocks per bucket, 512 threads each
#define GCHUNK 64             // dst nodes per gather block
#define GT 512                // threads per gather block
#define GGRID (NBUCKETS * 2)  // 782

__device__ inline unsigned f2bf(float f) {
    union { float f; unsigned u; } c; c.f = f;
    unsigned u = c.u;
    return (u + 0x7fffu + ((u >> 16) & 1u)) >> 16;
}

// ---------------- Kernel 1: fused convert + pooled2-zero + bin -------------------
__global__ __launch_bounds__(FB_THREADS) void bin_convert_kernel(
    const float* __restrict__ x,
    unsigned short* __restrict__ xb,      // may be null (skip convert)
    const int* __restrict__ edge_index,
    int* __restrict__ gcur,               // [NBUCKETS], pre-zeroed; ends as counts
    int* __restrict__ bucket,             // [NBUCKETS*CAP]
    float* __restrict__ pooled2)          // zeroed here (gather accumulates later)
{
    __shared__ int hist[NBUCKETS_PAD];
    __shared__ int gbase[NBUCKETS_PAD];

    int t = threadIdx.x;
    int blk = blockIdx.x;

    // phase 0a: zero pooled2 (64*128 floats)
    for (int i = blk * FB_THREADS + t; i < BATCHSIZE * D; i += FB_GRID * FB_THREADS)
        pooled2[i] = 0.0f;

    // phase 0b: grid-stride bf16 convert (8 floats -> one uint4 store)
    if (xb != nullptr) {
        const int TOT8 = N_NODES * D / 8;
        for (int i = blk * FB_THREADS + t; i < TOT8; i += FB_GRID * FB_THREADS) {
            float4 v0 = *(const float4*)(x + (size_t)i * 8);
            float4 v1 = *(const float4*)(x + (size_t)i * 8 + 4);
            uint4 pk;
            pk.x = f2bf(v0.x) | (f2bf(v0.y) << 16);
            pk.y = f2bf(v0.z) | (f2bf(v0.w) << 16);
            pk.z = f2bf(v1.x) | (f2bf(v1.y) << 16);
            pk.w = f2bf(v1.z) | (f2bf(v1.w) << 16);
            *(uint4*)(xb + (size_t)i * 8) = pk;
        }
    }

    // phase 1: full-range binning from register-held edges (no slicing)
    for (int i = t; i < NBUCKETS_PAD; i += FB_THREADS) hist[i] = 0;
    __syncthreads();

    int base = blk * FB_TILE;
    int lim = N_EDGES - base; if (lim > FB_TILE) lim = FB_TILE;

    int bkt[EPT];
    int pack[EPT];
#pragma unroll
    for (int j = 0; j < EPT / 4; ++j) {
        int e4 = (j * FB_THREADS + t) * 4;
#pragma unroll
        for (int k = 0; k < 4; ++k) bkt[j * 4 + k] = -1;
        if (e4 < lim) {                        // N_EDGES % 4 == 0, tiles 4-aligned
            int4 s4 = *(const int4*)(edge_index + base + e4);
            int4 d4 = *(const int4*)(edge_index + N_EDGES + base + e4);
            int ss[4] = { s4.x, s4.y, s4.z, s4.w };
            int dd[4] = { d4.x, d4.y, d4.z, d4.w };
#pragma unroll
            for (int k = 0; k < 4; ++k) {
                int b = dd[k] >> CHUNK_BITS;   // 0..390, always valid
                bkt[j * 4 + k] = b;
                pack[j * 4 + k] = (ss[k] << CHUNK_BITS) | (dd[k] & (CHUNK - 1));
                atomicAdd(&hist[b], 1);
            }
        }
    }
    __syncthreads();

    for (int i = t; i < NBUCKETS; i += FB_THREADS) {
        int c = hist[i];
        gbase[i] = c ? atomicAdd(&gcur[i], c) : 0;
        hist[i] = 0;                           // reuse as local cursor
    }
    __syncthreads();

#pragma unroll
    for (int k = 0; k < EPT; ++k) {
        int b = bkt[k];
        if (b >= 0) {
            int pos = gbase[b] + atomicAdd(&hist[b], 1);
            if (pos < CAP) bucket[(size_t)b * CAP + pos] = pack[k];
        }
    }
}

// ---------------- Kernel 2: half-bucket gather + fused pool GEMM ----------------
// 512 threads = 16 groups x 32 lanes; group owns 4 dsts (64 dsts/block).
// BF16 inner loop: uint4 per lane (16B = 8 feats), 16 lanes cover a 256B row,
// so a 32-lane group gathers 2 edges per load instruction -> 2x bytes in flight.
#define ACC8(u) do {                                                     \
    union { unsigned q; float f; } lo_, hi_;                             \
    lo_.q = (u).x << 16; hi_.q = (u).x & 0xffff0000u; a0 += lo_.f; a1 += hi_.f; \
    lo_.q = (u).y << 16; hi_.q = (u).y & 0xffff0000u; a2 += lo_.f; a3 += hi_.f; \
    lo_.q = (u).z << 16; hi_.q = (u).z & 0xffff0000u; a4 += lo_.f; a5 += hi_.f; \
    lo_.q = (u).w << 16; hi_.q = (u).w & 0xffff0000u; a6 += lo_.f; a7 += hi_.f; \
} while (0)

template<bool BF16>
__global__ __launch_bounds__(GT, 6) void gather_kernel(
    const float* __restrict__ x,
    const unsigned short* __restrict__ xb,
    const float* __restrict__ eps,
    const int* __restrict__ batch,
    const int* __restrict__ gcur,
    const int* __restrict__ bucket,
    const float* __restrict__ W,
    const float* __restrict__ b_pred,
    float* __restrict__ out,
    float* __restrict__ pooled2)
{
    __shared__ int   sorted[CAP];      // 9.6 KB
    __shared__ int   hist[GCHUNK];
    __shared__ int   offs[GCHUNK + 1];
    __shared__ int   cursor[GCHUNK];
    __shared__ float pool[8 * D];      // 4 KB
    __shared__ int   pcount[8];

    int blk = blockIdx.x;
    int c = blk >> 1;                  // bucket
    int h = blk & 1;                   // half
    int t = threadIdx.x;
    int lane = t & 31;
    int g = t >> 5;                    // 0..15
    int sub = lane >> 4;               // 0/1: which edge of the pair
    int li  = lane & 15;               // 16 lanes span one 256B bf16 row

    if (t < GCHUNK) hist[t] = 0;
    if (t < 8) pcount[t] = 0;
    for (int i = t; i < 8 * D; i += GT) pool[i] = 0.0f;
    int cnt = gcur[c];
    if (cnt > CAP) cnt = CAP;
    __syncthreads();

    const int hbase = h << 6;
    const int* brow = bucket + (size_t)c * CAP;

    // pass 1: histogram our half
    for (int i = t; i < cnt; i += GT) {
        int p = brow[i];
        int dloc = (p & (CHUNK - 1)) - hbase;
        if ((unsigned)dloc < (unsigned)GCHUNK) atomicAdd(&hist[dloc], 1);
    }
    __syncthreads();

    // exclusive scan over 64 bins (wave 0)
    if (t < GCHUNK) {
        int tot = hist[t];
        int incl = tot;
#pragma unroll
        for (int o = 1; o < 64; o <<= 1) {
            int y = __shfl_up(incl, o, 64);
            if (t >= o) incl += y;
        }
        offs[t] = incl - tot;
        cursor[t] = incl - tot;
        if (t == GCHUNK - 1) offs[GCHUNK] = incl;
    }
    __syncthreads();

    // pass 2: place srcs (bucket row re-read, L2-hot)
    for (int i = t; i < cnt; i += GT) {
        int p = brow[i];
        int dloc = (p & (CHUNK - 1)) - hbase;
        if ((unsigned)dloc < (unsigned)GCHUNK) {
            int pos = atomicAdd(&cursor[dloc], 1);
            sorted[pos] = p >> CHUNK_BITS;
        }
    }
    __syncthreads();

    int node0 = (c << CHUNK_BITS) + hbase;
    int bnode = node0 < N_NODES ? node0 : N_NODES - 1;
    int base_b = batch[bnode];
    float scale = 1.0f + eps[0];
    int dv_cur = -1;
    float4 ps = make_float4(0.f, 0.f, 0.f, 0.f);

    const int fo = BF16 ? (li * 8 + sub * 4) : (lane * 4);

#pragma unroll
    for (int k = 0; k < 4; ++k) {
        int dloc = 4 * g + k;
        int node = node0 + dloc;
        if (node >= N_NODES) break;
        int start = offs[dloc], end = offs[dloc + 1];
        float4 acc;
        if (BF16) {
            float a0 = 0.f, a1 = 0.f, a2 = 0.f, a3 = 0.f;
            float a4 = 0.f, a5 = 0.f, a6 = 0.f, a7 = 0.f;
            int i = start;
            for (; i + 16 <= end; i += 16) {
                int e0 = sorted[i + 0  + sub];
                int e1 = sorted[i + 2  + sub];
                int e2 = sorted[i + 4  + sub];
                int e3 = sorted[i + 6  + sub];
                int e4 = sorted[i + 8  + sub];
                int e5 = sorted[i + 10 + sub];
                int e6 = sorted[i + 12 + sub];
                int e7 = sorted[i + 14 + sub];
                uint4 u0 = *(const uint4*)(xb + (size_t)e0 * D + li * 8);
                uint4 u1 = *(const uint4*)(xb + (size_t)e1 * D + li * 8);
                uint4 u2 = *(const uint4*)(xb + (size_t)e2 * D + li * 8);
                uint4 u3 = *(const uint4*)(xb + (size_t)e3 * D + li * 8);
                uint4 u4 = *(const uint4*)(xb + (size_t)e4 * D + li * 8);
                uint4 u5 = *(const uint4*)(xb + (size_t)e5 * D + li * 8);
                uint4 u6 = *(const uint4*)(xb + (size_t)e6 * D + li * 8);
                uint4 u7 = *(const uint4*)(xb + (size_t)e7 * D + li * 8);
                ACC8(u0); ACC8(u1); ACC8(u2); ACC8(u3);
                ACC8(u4); ACC8(u5); ACC8(u6); ACC8(u7);
            }
            for (; i < end; i += 2) {
                int e = i + sub;
                if (e < end) {
                    uint4 u = *(const uint4*)(xb + (size_t)sorted[e] * D + li * 8);
                    ACC8(u);
                }
            }
            // combine the two edge-subsets (lane <-> lane^16 hold same features)
            a0 += __shfl_xor(a0, 16); a1 += __shfl_xor(a1, 16);
            a2 += __shfl_xor(a2, 16); a3 += __shfl_xor(a3, 16);
            a4 += __shfl_xor(a4, 16); a5 += __shfl_xor(a5, 16);
            a6 += __shfl_xor(a6, 16); a7 += __shfl_xor(a7, 16);
            acc = sub ? make_float4(a4, a5, a6, a7) : make_float4(a0, a1, a2, a3);
        } else {
            acc = make_float4(0.f, 0.f, 0.f, 0.f);
            int i = start;
            for (; i + 4 <= end; i += 4) {
                int s0 = sorted[i], s1 = sorted[i + 1];
                int s2 = sorted[i + 2], s3 = sorted[i + 3];
                const float4 v0 = *(const float4*)(x + (size_t)s0 * D + lane * 4);
                const float4 v1 = *(const float4*)(x + (size_t)s1 * D + lane * 4);
                const float4 v2 = *(const float4*)(x + (size_t)s2 * D + lane * 4);
                const float4 v3 = *(const float4*)(x + (size_t)s3 * D + lane * 4);
                acc.x += (v0.x + v1.x) + (v2.x + v3.x);
                acc.y += (v0.y + v1.y) + (v2.y + v3.y);
                acc.z += (v0.z + v1.z) + (v2.z + v3.z);
                acc.w += (v0.w + v1.w) + (v2.w + v3.w);
            }
            for (; i < end; ++i) {
                const float4 v0 = *(const float4*)(x + (size_t)sorted[i] * D + lane * 4);
                acc.x += v0.x; acc.y += v0.y; acc.z += v0.z; acc.w += v0.w;
            }
        }

        const float4 xv = *(const float4*)(x + (size_t)node * D + fo);
        float4 o;
        o.x = fmaxf(fmaf(scale, xv.x, acc.x), 0.0f);
        o.y = fmaxf(fmaf(scale, xv.y, acc.y), 0.0f);
        o.z = fmaxf(fmaf(scale, xv.z, acc.z), 0.0f);
        o.w = fmaxf(fmaf(scale, xv.w, acc.w), 0.0f);
        *(float4*)(out + (size_t)node * D + fo) = o;

        // fused per-batch pooling into LDS (batch spans <=2 per 64-node half)
        int dv = batch[node] - base_b;
        if (dv < 8) {
            if (dv != dv_cur) {
                if (dv_cur >= 0) {
                    float* pp = &pool[dv_cur * D + fo];
                    atomicAdd(pp + 0, ps.x); atomicAdd(pp + 1, ps.y);
                    atomicAdd(pp + 2, ps.z); atomicAdd(pp + 3, ps.w);
                }
                ps = make_float4(0.f, 0.f, 0.f, 0.f);
                dv_cur = dv;
            }
            ps.x += o.x; ps.y += o.y; ps.z += o.z; ps.w += o.w;
            if (lane == 0) atomicAdd(&pcount[dv], 1);
        }
    }
    if (dv_cur >= 0) {
        float* pp = &pool[dv_cur * D + fo];
        atomicAdd(pp + 0, ps.x); atomicAdd(pp + 1, ps.y);
        atomicAdd(pp + 2, ps.z); atomicAdd(pp + 3, ps.w);
    }
    __syncthreads();

    // fused pool GEMM epilogue: pooled2[base_b+dv] += pool[dv] @ W + pcount*b_pred
    int lastnode = node0 + GCHUNK - 1;
    if (lastnode >= N_NODES) lastnode = N_NODES - 1;
    int used = batch[lastnode] - base_b + 1;
    if (used > 8) used = 8;
    if (used < 0) used = 0;
    if (t < D) {
        for (int dv = 0; dv < used; ++dv) {
            float acc = (float)pcount[dv] * b_pred[t];
            const float* prow = &pool[dv * D];
#pragma unroll 8
            for (int k = 0; k < D; ++k) {
                acc = fmaf(prow[k], W[(size_t)k * D + t], acc);
            }
            atomicAdd(&pooled2[(size_t)(base_b + dv) * D + t], acc);
        }
    }
}

// ---------------- tiny-ws fallback (round-1) ----------------

__global__ void edge_scatter_kernel(const float* __restrict__ x,
                                    const int* __restrict__ edge_index,
                                    float* __restrict__ agg) {
    int tid = blockIdx.x * blockDim.x + threadIdx.x;
    int lane = tid & 31;
    int e = tid >> 5;
    if (e >= N_EDGES) return;
    int src = edge_index[e];
    int dst = edge_index[N_EDGES + e];
    const float4 v = *(const float4*)(x + (size_t)src * D + lane * 4);
    float* dp = agg + (size_t)dst * D + lane * 4;
    atomicAdd(dp + 0, v.x);
    atomicAdd(dp + 1, v.y);
    atomicAdd(dp + 2, v.z);
    atomicAdd(dp + 3, v.w);
}

__global__ void finalize_kernel(const float* __restrict__ x,
                                const float* __restrict__ eps,
                                const int* __restrict__ batch,
                                float* __restrict__ out,
                                float* __restrict__ Sf,
                                float* __restrict__ counts) {
    int tid = blockIdx.x * blockDim.x + threadIdx.x;
    int lane = tid & 31;
    int node = tid >> 5;
    if (node >= N_NODES) return;
    float scale = 1.0f + eps[0];
    const float4 xv = *(const float4*)(x + (size_t)node * D + lane * 4);
    float4 av = *(float4*)(out + (size_t)node * D + lane * 4);
    float4 o;
    o.x = fmaxf(fmaf(scale, xv.x, av.x), 0.0f);
    o.y = fmaxf(fmaf(scale, xv.y, av.y), 0.0f);
    o.z = fmaxf(fmaf(scale, xv.z, av.z), 0.0f);
    o.w = fmaxf(fmaf(scale, xv.w, av.w), 0.0f);
    *(float4*)(out + (size_t)node * D + lane * 4) = o;
    int b = batch[node];
    float* sp = Sf + (size_t)b * D + lane * 4;
    atomicAdd(sp + 0, o.x);
    atomicAdd(sp + 1, o.y);
    atomicAdd(sp + 2, o.z);
    atomicAdd(sp + 3, o.w);
    if (lane == 0) atomicAdd(counts + b, 1.0f);
}

__global__ void pool_gemm_fallback_kernel(const float* __restrict__ Sf,
                                          const float* __restrict__ counts,
                                          const float* __restrict__ W,
                                          const float* __restrict__ b_pred,
                                          float* __restrict__ pooled2) {
    int b = blockIdx.x;
    int j = threadIdx.x;
    float acc = counts[b] * b_pred[j];
    const float* srow = Sf + (size_t)b * D;
#pragma unroll 8
    for (int k = 0; k < D; ++k) {
        acc = fmaf(srow[k], W[(size_t)k * D + j], acc);
    }
    pooled2[(size_t)b * D + j] = acc;
}

extern "C" void kernel_launch(void* const* d_in, const int* in_sizes, int n_in,
                              void* d_out, int out_size, void* d_ws, size_t ws_size,
                              hipStream_t stream) {
    const float* x      = (const float*)d_in[0];
    const float* eps    = (const float*)d_in[1];
    const float* W_pred = (const float*)d_in[2];
    const float* b_pred = (const float*)d_in[3];
    const int*   eidx   = (const int*)d_in[4];
    const int*   batch  = (const int*)d_in[5];

    float* out     = (float*)d_out;
    float* pooled2 = (float*)d_out + (size_t)N_NODES * D;

    // ws layout (4B units): gcur[392] | bucket[NBUCKETS*CAP] | xb[N*D/2]
    const size_t base_ints = (size_t)NBUCKETS_PAD + (size_t)NBUCKETS * CAP;
    const size_t need_mid  = base_ints * 4;
    const size_t need_full = (base_ints + (size_t)N_NODES * D / 2) * 4;

    if (ws_size >= need_mid) {
        int* gcur   = (int*)d_ws;
        int* bucket = (int*)d_ws + NBUCKETS_PAD;
        bool full = (ws_size >= need_full);
        unsigned short* xb = full ? (unsigned short*)((int*)d_ws + base_ints) : nullptr;

        hipMemsetAsync(gcur, 0, (size_t)NBUCKETS_PAD * 4, stream);

        bin_convert_kernel<<<FB_GRID, FB_THREADS, 0, stream>>>(
            x, xb, eidx, gcur, bucket, pooled2);
        if (full) {
            gather_kernel<true><<<GGRID, GT, 0, stream>>>(
                x, xb, eps, batch, gcur, bucket, W_pred, b_pred, out, pooled2);
        } else {
            gather_kernel<false><<<GGRID, GT, 0, stream>>>(
                x, (const unsigned short*)nullptr, eps, batch, gcur, bucket,
                W_pred, b_pred, out, pooled2);
        }
    } else {
        float* Sf      = (float*)d_ws;
        float* countsf = (float*)d_ws + BATCHSIZE * D;
        hipMemsetAsync(out, 0, (size_t)N_NODES * D * sizeof(float), stream);
        hipMemsetAsync(d_ws, 0, (BATCHSIZE * D + BATCHSIZE) * sizeof(float), stream);
        {
            long long total = (long long)N_EDGES * 32;
            int blocks = (int)((total + 255) / 256);
            edge_scatter_kernel<<<blocks, 256, 0, stream>>>(x, eidx, out);
        }
        {
            long long total = (long long)N_NODES * 32;
            int blocks = (int)((total + 255) / 256);
            finalize_kernel<<<blocks, 256, 0, stream>>>(x, eps, batch, out, Sf, countsf);
        }
        pool_gemm_fallback_kernel<<<BATCHSIZE, D, 0, stream>>>(Sf, countsf, W_pred, b_pred, pooled2);
    }
}

// Round 4
// 145.785 us; speedup vs baseline: 1.2552x; 1.2552x over previous
//
#include <hip/hip_runtime.h>
#include <hip/hip_bf16.h>

#define N_NODES 50000
#define N_EDGES 800000
#define D 128
#define BATCHSIZE 64

// Coarse binning: 128 dst-nodes per bucket
#define CHUNK_BITS 7
#define CHUNK 128
#define NBUCKETS 391          // ceil(50000/128)
#define NBUCKETS_PAD 392
#define CAP 2400              // mean 2048 + ~7.8 sigma (proven)
#define GS_PAD 16             // gcur stride when padded: 1 counter per 64B line

// bin: de-sliced, 391 tiles x 2048 edges, full-range histogram per block
#define FB_TILE 2048
#define NTILES ((N_EDGES + FB_TILE - 1) / FB_TILE)   // 391
#define FB_THREADS 256
#define FB_GRID NTILES                                // 391
#define EPT 8                 // edges per thread (2048/256)

__device__ inline unsigned f2bf(float f) {
    union { float f; unsigned u; } c; c.f = f;
    unsigned u = c.u;
    return (u + 0x7fffu + ((u >> 16) & 1u)) >> 16;
}

__device__ inline float4 bf4_to_f4(uint2 u) {
    union { unsigned u; float f; } a, b, c, d;
    a.u = u.x << 16; b.u = u.x & 0xffff0000u;
    c.u = u.y << 16; d.u = u.y & 0xffff0000u;
    float4 r; r.x = a.f; r.y = b.f; r.z = c.f; r.w = d.f;
    return r;
}

// ---------------- Kernel 1: fused convert + pooled2-zero + bin -------------------
__global__ __launch_bounds__(FB_THREADS) void bin_convert_kernel(
    const float* __restrict__ x,
    unsigned short* __restrict__ xb,      // may be null (skip convert)
    const int* __restrict__ edge_index,
    int* __restrict__ gcur,               // [NBUCKETS*gs], pre-zeroed; ends as counts
    int* __restrict__ bucket,             // [NBUCKETS*CAP]
    float* __restrict__ pooled2,          // zeroed here (gather accumulates later)
    int gs)                               // gcur stride (16 = padded, 1 = legacy)
{
    __shared__ int hist[NBUCKETS_PAD];
    __shared__ int gbase[NBUCKETS_PAD];

    int t = threadIdx.x;
    int blk = blockIdx.x;

    // phase 0a: zero pooled2 (64*128 floats)
    for (int i = blk * FB_THREADS + t; i < BATCHSIZE * D; i += FB_GRID * FB_THREADS)
        pooled2[i] = 0.0f;

    // phase 0b: grid-stride bf16 convert (8 floats -> one uint4 store)
    if (xb != nullptr) {
        const int TOT8 = N_NODES * D / 8;
        for (int i = blk * FB_THREADS + t; i < TOT8; i += FB_GRID * FB_THREADS) {
            float4 v0 = *(const float4*)(x + (size_t)i * 8);
            float4 v1 = *(const float4*)(x + (size_t)i * 8 + 4);
            uint4 pk;
            pk.x = f2bf(v0.x) | (f2bf(v0.y) << 16);
            pk.y = f2bf(v0.z) | (f2bf(v0.w) << 16);
            pk.z = f2bf(v1.x) | (f2bf(v1.y) << 16);
            pk.w = f2bf(v1.z) | (f2bf(v1.w) << 16);
            *(uint4*)(xb + (size_t)i * 8) = pk;
        }
    }

    // phase 1: full-range binning from register-held edges
    for (int i = t; i < NBUCKETS_PAD; i += FB_THREADS) hist[i] = 0;
    __syncthreads();

    int base = blk * FB_TILE;
    int lim = N_EDGES - base; if (lim > FB_TILE) lim = FB_TILE;

    int bkt[EPT];
    int pack[EPT];
#pragma unroll
    for (int j = 0; j < EPT / 4; ++j) {
        int e4 = (j * FB_THREADS + t) * 4;
#pragma unroll
        for (int k = 0; k < 4; ++k) bkt[j * 4 + k] = -1;
        if (e4 < lim) {                        // N_EDGES % 4 == 0, tiles 4-aligned
            int4 s4 = *(const int4*)(edge_index + base + e4);
            int4 d4 = *(const int4*)(edge_index + N_EDGES + base + e4);
            int ss[4] = { s4.x, s4.y, s4.z, s4.w };
            int dd[4] = { d4.x, d4.y, d4.z, d4.w };
#pragma unroll
            for (int k = 0; k < 4; ++k) {
                int b = dd[k] >> CHUNK_BITS;   // 0..390, always valid
                bkt[j * 4 + k] = b;
                pack[j * 4 + k] = (ss[k] << CHUNK_BITS) | (dd[k] & (CHUNK - 1));
                atomicAdd(&hist[b], 1);
            }
        }
    }
    __syncthreads();

    // reserve global space: one padded counter per 64B line kills the
    // 16-counters-per-line serialization (391 blocks x 391 counters of RMWs)
    for (int i = t; i < NBUCKETS; i += FB_THREADS) {
        int c = hist[i];
        gbase[i] = c ? atomicAdd(&gcur[i * gs], c) : 0;
        hist[i] = 0;                           // reuse as local cursor
    }
    __syncthreads();

#pragma unroll
    for (int k = 0; k < EPT; ++k) {
        int b = bkt[k];
        if (b >= 0) {
            int pos = gbase[b] + atomicAdd(&hist[b], 1);
            if (pos < CAP) bucket[(size_t)b * CAP + pos] = pack[k];
        }
    }
}

// ---------------- Kernel 2: full-bucket gather (proven round-1 form) -------------
// 1024 threads = 32 groups x 32 lanes; group owns 4 dsts exclusively.
template<bool BF16>
__global__ __launch_bounds__(1024) void gather_kernel(
    const float* __restrict__ x,
    const unsigned short* __restrict__ xb,
    const float* __restrict__ eps,
    const int* __restrict__ batch,
    const int* __restrict__ gcur,
    const int* __restrict__ bucket,
    const float* __restrict__ W,
    const float* __restrict__ b_pred,
    float* __restrict__ out,
    float* __restrict__ pooled2,
    int gs)
{
    __shared__ int   ebuf[CAP];        // 9.6 KB
    __shared__ int   sorted[CAP];      // 9.6 KB
    __shared__ int   hist[CHUNK];
    __shared__ int   offs[CHUNK + 1];
    __shared__ int   cursor[CHUNK];
    __shared__ float pool[8 * D];      // 4 KB
    __shared__ int   pcount[8];

    int c = blockIdx.x;
    int t = threadIdx.x;
    int lane = t & 31;
    int g = t >> 5;

    if (t < CHUNK) hist[t] = 0;
    if (t < 8) pcount[t] = 0;
    for (int i = t; i < 8 * D; i += 1024) pool[i] = 0.0f;
    int cnt = gcur[(size_t)c * gs];
    if (cnt > CAP) cnt = CAP;
    __syncthreads();

    for (int i = t; i < cnt; i += 1024) {
        int p = bucket[(size_t)c * CAP + i];
        ebuf[i] = p;
        atomicAdd(&hist[p & (CHUNK - 1)], 1);
    }
    __syncthreads();

    if (t < 64) {
        int h0 = hist[2 * t], h1 = hist[2 * t + 1];
        int tot = h0 + h1;
        int incl = tot;
#pragma unroll
        for (int o = 1; o < 64; o <<= 1) {
            int y = __shfl_up(incl, o, 64);
            if (t >= o) incl += y;
        }
        int excl = incl - tot;
        offs[2 * t] = excl;          cursor[2 * t] = excl;
        offs[2 * t + 1] = excl + h0; cursor[2 * t + 1] = excl + h0;
        if (t == 63) offs[CHUNK] = incl;
    }
    __syncthreads();

    for (int i = t; i < cnt; i += 1024) {
        int p = ebuf[i];
        int pos = atomicAdd(&cursor[p & (CHUNK - 1)], 1);
        sorted[pos] = p >> CHUNK_BITS;
    }
    __syncthreads();

    int node0 = c << CHUNK_BITS;
    int base_b = batch[node0];
    float scale = 1.0f + eps[0];
    int dv_cur = -1;
    float4 ps = make_float4(0.f, 0.f, 0.f, 0.f);

#pragma unroll
    for (int k = 0; k < 4; ++k) {
        int d = 4 * g + k;
        int node = node0 + d;
        if (node >= N_NODES) break;
        int start = offs[d], end = offs[d + 1];
        float4 acc = make_float4(0.f, 0.f, 0.f, 0.f);
        int i = start;
        if (BF16) {
            for (; i + 4 <= end; i += 4) {
                int s0 = sorted[i], s1 = sorted[i + 1];
                int s2 = sorted[i + 2], s3 = sorted[i + 3];
                uint2 u0 = *(const uint2*)(xb + (size_t)s0 * D + lane * 4);
                uint2 u1 = *(const uint2*)(xb + (size_t)s1 * D + lane * 4);
                uint2 u2 = *(const uint2*)(xb + (size_t)s2 * D + lane * 4);
                uint2 u3 = *(const uint2*)(xb + (size_t)s3 * D + lane * 4);
                float4 v0 = bf4_to_f4(u0), v1 = bf4_to_f4(u1);
                float4 v2 = bf4_to_f4(u2), v3 = bf4_to_f4(u3);
                acc.x += (v0.x + v1.x) + (v2.x + v3.x);
                acc.y += (v0.y + v1.y) + (v2.y + v3.y);
                acc.z += (v0.z + v1.z) + (v2.z + v3.z);
                acc.w += (v0.w + v1.w) + (v2.w + v3.w);
            }
            for (; i < end; ++i) {
                uint2 u0 = *(const uint2*)(xb + (size_t)sorted[i] * D + lane * 4);
                float4 v0 = bf4_to_f4(u0);
                acc.x += v0.x; acc.y += v0.y; acc.z += v0.z; acc.w += v0.w;
            }
        } else {
            for (; i + 4 <= end; i += 4) {
                int s0 = sorted[i], s1 = sorted[i + 1];
                int s2 = sorted[i + 2], s3 = sorted[i + 3];
                const float4 v0 = *(const float4*)(x + (size_t)s0 * D + lane * 4);
                const float4 v1 = *(const float4*)(x + (size_t)s1 * D + lane * 4);
                const float4 v2 = *(const float4*)(x + (size_t)s2 * D + lane * 4);
                const float4 v3 = *(const float4*)(x + (size_t)s3 * D + lane * 4);
                acc.x += (v0.x + v1.x) + (v2.x + v3.x);
                acc.y += (v0.y + v1.y) + (v2.y + v3.y);
                acc.z += (v0.z + v1.z) + (v2.z + v3.z);
                acc.w += (v0.w + v1.w) + (v2.w + v3.w);
            }
            for (; i < end; ++i) {
                const float4 v0 = *(const float4*)(x + (size_t)sorted[i] * D + lane * 4);
                acc.x += v0.x; acc.y += v0.y; acc.z += v0.z; acc.w += v0.w;
            }
        }
        const float4 xv = *(const float4*)(x + (size_t)node * D + lane * 4);
        float4 o;
        o.x = fmaxf(fmaf(scale, xv.x, acc.x), 0.0f);
        o.y = fmaxf(fmaf(scale, xv.y, acc.y), 0.0f);
        o.z = fmaxf(fmaf(scale, xv.z, acc.z), 0.0f);
        o.w = fmaxf(fmaf(scale, xv.w, acc.w), 0.0f);
        *(float4*)(out + (size_t)node * D + lane * 4) = o;

        // fused per-batch pooling into LDS (batch spans <=2 per 128-node chunk)
        int dv = batch[node] - base_b;
        if (dv < 8) {
            if (dv != dv_cur) {
                if (dv_cur >= 0) {
                    float* pp = &pool[dv_cur * D + lane * 4];
                    atomicAdd(pp + 0, ps.x); atomicAdd(pp + 1, ps.y);
                    atomicAdd(pp + 2, ps.z); atomicAdd(pp + 3, ps.w);
                }
                ps = make_float4(0.f, 0.f, 0.f, 0.f);
                dv_cur = dv;
            }
            ps.x += o.x; ps.y += o.y; ps.z += o.z; ps.w += o.w;
            if (lane == 0) atomicAdd(&pcount[dv], 1);
        }
    }
    if (dv_cur >= 0) {
        float* pp = &pool[dv_cur * D + lane * 4];
        atomicAdd(pp + 0, ps.x); atomicAdd(pp + 1, ps.y);
        atomicAdd(pp + 2, ps.z); atomicAdd(pp + 3, ps.w);
    }
    __syncthreads();

    // fused pool GEMM epilogue: pooled2[base_b+dv] += pool[dv] @ W + pcount*b_pred
    int lastnode = node0 + CHUNK - 1;
    if (lastnode >= N_NODES) lastnode = N_NODES - 1;
    int used = batch[lastnode] - base_b + 1;
    if (used > 8) used = 8;
    if (t < D) {
        for (int dv = 0; dv < used; ++dv) {
            float acc = (float)pcount[dv] * b_pred[t];
            const float* prow = &pool[dv * D];
#pragma unroll 8
            for (int k = 0; k < D; ++k) {
                acc = fmaf(prow[k], W[(size_t)k * D + t], acc);
            }
            atomicAdd(&pooled2[(size_t)(base_b + dv) * D + t], acc);
        }
    }
}

// ---------------- tiny-ws fallback (round-1) ----------------

__global__ void edge_scatter_kernel(const float* __restrict__ x,
                                    const int* __restrict__ edge_index,
                                    float* __restrict__ agg) {
    int tid = blockIdx.x * blockDim.x + threadIdx.x;
    int lane = tid & 31;
    int e = tid >> 5;
    if (e >= N_EDGES) return;
    int src = edge_index[e];
    int dst = edge_index[N_EDGES + e];
    const float4 v = *(const float4*)(x + (size_t)src * D + lane * 4);
    float* dp = agg + (size_t)dst * D + lane * 4;
    atomicAdd(dp + 0, v.x);
    atomicAdd(dp + 1, v.y);
    atomicAdd(dp + 2, v.z);
    atomicAdd(dp + 3, v.w);
}

__global__ void finalize_kernel(const float* __restrict__ x,
                                const float* __restrict__ eps,
                                const int* __restrict__ batch,
                                float* __restrict__ out,
                                float* __restrict__ Sf,
                                float* __restrict__ counts) {
    int tid = blockIdx.x * blockDim.x + threadIdx.x;
    int lane = tid & 31;
    int node = tid >> 5;
    if (node >= N_NODES) return;
    float scale = 1.0f + eps[0];
    const float4 xv = *(const float4*)(x + (size_t)node * D + lane * 4);
    float4 av = *(float4*)(out + (size_t)node * D + lane * 4);
    float4 o;
    o.x = fmaxf(fmaf(scale, xv.x, av.x), 0.0f);
    o.y = fmaxf(fmaf(scale, xv.y, av.y), 0.0f);
    o.z = fmaxf(fmaf(scale, xv.z, av.z), 0.0f);
    o.w = fmaxf(fmaf(scale, xv.w, av.w), 0.0f);
    *(float4*)(out + (size_t)node * D + lane * 4) = o;
    int b = batch[node];
    float* sp = Sf + (size_t)b * D + lane * 4;
    atomicAdd(sp + 0, o.x);
    atomicAdd(sp + 1, o.y);
    atomicAdd(sp + 2, o.z);
    atomicAdd(sp + 3, o.w);
    if (lane == 0) atomicAdd(counts + b, 1.0f);
}

__global__ void pool_gemm_fallback_kernel(const float* __restrict__ Sf,
                                          const float* __restrict__ counts,
                                          const float* __restrict__ W,
                                          const float* __restrict__ b_pred,
                                          float* __restrict__ pooled2) {
    int b = blockIdx.x;
    int j = threadIdx.x;
    float acc = counts[b] * b_pred[j];
    const float* srow = Sf + (size_t)b * D;
#pragma unroll 8
    for (int k = 0; k < D; ++k) {
        acc = fmaf(srow[k], W[(size_t)k * D + j], acc);
    }
    pooled2[(size_t)b * D + j] = acc;
}

extern "C" void kernel_launch(void* const* d_in, const int* in_sizes, int n_in,
                              void* d_out, int out_size, void* d_ws, size_t ws_size,
                              hipStream_t stream) {
    const float* x      = (const float*)d_in[0];
    const float* eps    = (const float*)d_in[1];
    const float* W_pred = (const float*)d_in[2];
    const float* b_pred = (const float*)d_in[3];
    const int*   eidx   = (const int*)d_in[4];
    const int*   batch  = (const int*)d_in[5];

    float* out     = (float*)d_out;
    float* pooled2 = (float*)d_out + (size_t)N_NODES * D;

    // ws layouts (4B units), preferred first:
    //   padded: gcur[392*16] | bucket[NBUCKETS*CAP] | xb[N*D/2 shorts]
    //   legacy: gcur[392]    | bucket[NBUCKETS*CAP] | xb
    const size_t xb_ints = (size_t)N_NODES * D / 2;   // 3.2M ints = 12.8 MB
    const size_t buck    = (size_t)NBUCKETS * CAP;

    const size_t need_pad_full  = ((size_t)NBUCKETS_PAD * GS_PAD + buck + xb_ints) * 4;
    const size_t need_full      = ((size_t)NBUCKETS_PAD + buck + xb_ints) * 4;
    const size_t need_pad_mid   = ((size_t)NBUCKETS_PAD * GS_PAD + buck) * 4;
    const size_t need_mid       = ((size_t)NBUCKETS_PAD + buck) * 4;

    if (ws_size >= need_mid) {
        int gs = (ws_size >= (ws_size >= need_full ? need_pad_full : need_pad_mid))
                     ? GS_PAD : 1;
        size_t gcur_ints = (size_t)NBUCKETS_PAD * gs;
        int* gcur   = (int*)d_ws;
        int* bucket = (int*)d_ws + gcur_ints;
        bool full = (ws_size >= (gs == GS_PAD ? need_pad_full : need_full));
        unsigned short* xb = full
            ? (unsigned short*)((int*)d_ws + gcur_ints + buck) : nullptr;

        hipMemsetAsync(gcur, 0, gcur_ints * 4, stream);

        bin_convert_kernel<<<FB_GRID, FB_THREADS, 0, stream>>>(
            x, xb, eidx, gcur, bucket, pooled2, gs);
        if (full) {
            gather_kernel<true><<<NBUCKETS, 1024, 0, stream>>>(
                x, xb, eps, batch, gcur, bucket, W_pred, b_pred, out, pooled2, gs);
        } else {
            gather_kernel<false><<<NBUCKETS, 1024, 0, stream>>>(
                x, (const unsigned short*)nullptr, eps, batch, gcur, bucket,
                W_pred, b_pred, out, pooled2, gs);
        }
    } else {
        float* Sf      = (float*)d_ws;
        float* countsf = (float*)d_ws + BATCHSIZE * D;
        hipMemsetAsync(out, 0, (size_t)N_NODES * D * sizeof(float), stream);
        hipMemsetAsync(d_ws, 0, (BATCHSIZE * D + BATCHSIZE) * sizeof(float), stream);
        {
            long long total = (long long)N_EDGES * 32;
            int blocks = (int)((total + 255) / 256);
            edge_scatter_kernel<<<blocks, 256, 0, stream>>>(x, eidx, out);
        }
        {
            long long total = (long long)N_NODES * 32;
            int blocks = (int)((total + 255) / 256);
            finalize_kernel<<<blocks, 256, 0, stream>>>(x, eps, batch, out, Sf, countsf);
        }
        pool_gemm_fallback_kernel<<<BATCHSIZE, D, 0, stream>>>(Sf, countsf, W_pred, b_pred, pooled2);
    }
}